// Round 1
// baseline (6552.724 us; speedup 1.0000x reference)
//
#include <hip/hip_runtime.h>
#include <hip/hip_bf16.h>
#include <type_traits>
#include <stdint.h>

using bf16 = __hip_bfloat16;

// ---------- helpers ----------
template <typename T>
__device__ inline float ldf(const T* p) {
  if constexpr (std::is_same<T, bf16>::value) return __bfloat162float(*p);
  else return *p;
}
template <typename T>
__device__ inline void stf(T* p, float v) {
  if constexpr (std::is_same<T, bf16>::value) *p = __float2bfloat16(v);
  else *p = v;
}

// ---------- 3x3 conv, Cin=Cout=128, SAME pad, NCHW input ----------
// OMODE 0: out[b][co][h][w]          (NCHW)
// OMODE 1: out[b][w][h][co]          (gather-friendly K/V layout)
// OMODE 2: out[b][h*W+w][co]         (q layout: (b, s, e))
// Block: 2 output rows x 32 cols x 128 Cout. 256 threads,
// each thread: 4 px x 8 co. ci chunked by 8 (16 chunks).
template <typename Tin, typename Tout, int OMODE, bool RELU>
__global__ __launch_bounds__(256)
void conv3x3_k(const Tin* __restrict__ in, const float* __restrict__ wgt,
               const float* __restrict__ bias, Tout* __restrict__ out,
               int H, int W) {
  __shared__ float s_in[8][4][36];   // [ci][row r0-1..r0+2][col c0-1..c0+32]
  __shared__ float s_w[8 * 128 * 9]; // [ci][co][tap]
  const int b  = blockIdx.z;
  const int r0 = blockIdx.y * 2;
  const int c0 = blockIdx.x * 32;
  const int tid = threadIdx.x;
  const int pxg = tid & 15, cog = tid >> 4;
  const int orow  = pxg >> 3;        // 0..1
  const int cbase = (pxg & 7) * 4;   // 0..28

  float acc[4][8];
#pragma unroll
  for (int p = 0; p < 4; ++p)
#pragma unroll
    for (int i = 0; i < 8; ++i) acc[p][i] = 0.f;

  const Tin* inb = in + (size_t)b * 128 * H * W;

  for (int chunk = 0; chunk < 16; ++chunk) {
    __syncthreads();
    // stage input: 8 ci x 4 rows x 34 cols (zero-pad at image edges)
    for (int i = tid; i < 8 * 136; i += 256) {
      int ci = i / 136; int rem = i - ci * 136;
      int ry = rem / 34; int cx = rem - ry * 34;
      int gr = r0 - 1 + ry, gc = c0 - 1 + cx;
      float v = 0.f;
      if (gr >= 0 && gr < H && gc >= 0 && gc < W)
        v = ldf(&inb[((size_t)(chunk * 8 + ci) * H + gr) * W + gc]);
      s_in[ci][ry][cx] = v;
    }
    // stage weights: 128 co x 8 ci x 9 taps
    for (int i = tid; i < 128 * 72; i += 256) {
      int co = i / 72; int rem = i - co * 72;
      int ci = rem / 9; int tap = rem - ci * 9;
      s_w[(ci * 128 + co) * 9 + tap] =
          wgt[((size_t)co * 128 + chunk * 8 + ci) * 9 + tap];
    }
    __syncthreads();

    for (int ci = 0; ci < 8; ++ci) {
      float iv[3][6];
#pragma unroll
      for (int ky = 0; ky < 3; ++ky)
#pragma unroll
        for (int t = 0; t < 6; ++t)
          iv[ky][t] = s_in[ci][orow + ky][cbase + t];
#pragma unroll
      for (int coi = 0; coi < 8; ++coi) {
        const float* wp = &s_w[(ci * 128 + cog * 8 + coi) * 9];
        float wv[9];
#pragma unroll
        for (int t = 0; t < 9; ++t) wv[t] = wp[t];
#pragma unroll
        for (int p = 0; p < 4; ++p)
#pragma unroll
          for (int ky = 0; ky < 3; ++ky)
#pragma unroll
            for (int kx = 0; kx < 3; ++kx)
              acc[p][coi] = fmaf(iv[ky][p + kx], wv[ky * 3 + kx], acc[p][coi]);
      }
    }
  }

  const int gr = r0 + orow;
#pragma unroll
  for (int coi = 0; coi < 8; ++coi) {
    const int co = cog * 8 + coi;
    const float bv = bias[co];
#pragma unroll
    for (int p = 0; p < 4; ++p) {
      const int gc = c0 + cbase + p;
      float v = acc[p][coi] + bv;
      if (RELU) v = fmaxf(v, 0.f);
      size_t idx;
      if (OMODE == 0)      idx = (((size_t)b * 128 + co) * H + gr) * W + gc;
      else if (OMODE == 1) idx = (((size_t)b * W + gc) * H + gr) * 128 + co;
      else                 idx = (((size_t)b * H + gr) * W + gc) * 128 + co;
      stf(&out[idx], v);
    }
  }
}

// ---------- attention: dot + softmax ----------
// one block per (b, s); 128 threads = one h each.
__global__ __launch_bounds__(128)
void attn_dot_k(const float* __restrict__ qg, const bf16* __restrict__ Kg,
                const int* __restrict__ u, float* __restrict__ pout) {
  const int bs = blockIdx.x;
  const int b = bs >> 10;
  const int tid = threadIdx.x; // h
  __shared__ float sq[128];
  __shared__ float sd[128];
  sq[tid] = qg[(size_t)bs * 128 + tid];
  int w = u[bs]; w = w < 0 ? 0 : (w > 511 ? 511 : w);
  __syncthreads();
  const uint32_t* kp = reinterpret_cast<const uint32_t*>(
      Kg + (((size_t)b * 512 + w) * 128 + tid) * 128);
  float acc = 0.f;
#pragma unroll 8
  for (int i = 0; i < 64; ++i) {
    uint32_t v = kp[i];
    acc = fmaf(sq[2 * i],     __uint_as_float(v << 16), acc);
    acc = fmaf(sq[2 * i + 1], __uint_as_float(v & 0xffff0000u), acc);
  }
  sd[tid] = acc * 0.17677669529663687f; // 32^-0.5
  __syncthreads();
  float mx = -1e30f;
  for (int i = 0; i < 128; ++i) mx = fmaxf(mx, sd[i]);
  float e = expf(sd[tid] - mx);
  __syncthreads();
  sd[tid] = e;
  __syncthreads();
  float sum = 0.f;
  for (int i = 0; i < 128; ++i) sum += sd[i];
  pout[(size_t)bs * 128 + tid] = e / sum;
}

// ---------- attention: P @ V_gathered ----------
// one block per (b, s); 128 threads = one e each. Writes a in NCHW.
__global__ __launch_bounds__(128)
void attn_pv_k(const float* __restrict__ pin, const bf16* __restrict__ Vg,
               const int* __restrict__ u, float* __restrict__ aout) {
  const int bs = blockIdx.x;
  const int b = bs >> 10, s = bs & 1023;
  const int tid = threadIdx.x; // e
  __shared__ float sp[128];
  sp[tid] = pin[(size_t)bs * 128 + tid];
  int w = u[bs]; w = w < 0 ? 0 : (w > 511 ? 511 : w);
  __syncthreads();
  const unsigned short* vp = reinterpret_cast<const unsigned short*>(
      Vg + ((size_t)b * 512 + w) * 16384) + tid;
  float acc = 0.f;
#pragma unroll 8
  for (int h = 0; h < 128; ++h)
    acc = fmaf(sp[h], __uint_as_float(((uint32_t)vp[h * 128]) << 16), acc);
  aout[((size_t)b * 128 + tid) * 1024 + s] = acc;
}

// ---------- launch ----------
extern "C" void kernel_launch(void* const* d_in, const int* in_sizes, int n_in,
                              void* d_out, int out_size, void* d_ws, size_t ws_size,
                              hipStream_t stream) {
  const float* x      = (const float*)d_in[0];
  const float* y      = (const float*)d_in[1];
  const int*   u      = (const int*)d_in[2];
  const float* q_w1   = (const float*)d_in[3];
  const float* q_b1   = (const float*)d_in[4];
  const float* q_w2   = (const float*)d_in[5];
  const float* q_b2   = (const float*)d_in[6];
  const float* k_w1   = (const float*)d_in[7];
  const float* k_b1   = (const float*)d_in[8];
  const float* k_w2   = (const float*)d_in[9];
  const float* k_b2   = (const float*)d_in[10];
  const float* v_w1   = (const float*)d_in[11];
  const float* v_b1   = (const float*)d_in[12];
  const float* v_w2   = (const float*)d_in[13];
  const float* v_b2   = (const float*)d_in[14];
  const float* proj_w = (const float*)d_in[15];
  const float* proj_b = (const float*)d_in[16];
  float* out = (float*)d_out;

  char* ws = (char*)d_ws;
  const size_t BIG = (size_t)4 * 128 * 128 * 512 * sizeof(bf16); // 67,108,864
  bf16*  bufA = (bf16*)ws;                 // k1 / v1 (NCHW bf16)
  bf16*  bufB = (bf16*)(ws + BIG);         // K / V in (b,w,h,e) bf16
  float* t1   = (float*)(ws + 2 * BIG);                    // 2 MB
  float* qg   = (float*)(ws + 2 * BIG + 1 * 2097152);      // 2 MB
  float* pb   = (float*)(ws + 2 * BIG + 2 * 2097152);      // 2 MB
  float* ab   = (float*)(ws + 2 * BIG + 3 * 2097152);      // 2 MB

  dim3 blk(256);
  dim3 gx(1, 16, 4);   // 32x32 images
  dim3 gy(16, 64, 4);  // 512x128 images

  // Q path
  conv3x3_k<float, float, 0, true ><<<gx, blk, 0, stream>>>(x,  q_w1, q_b1, t1, 32, 32);
  conv3x3_k<float, float, 2, false><<<gx, blk, 0, stream>>>(t1, q_w2, q_b2, qg, 32, 32);
  // K path
  conv3x3_k<float, bf16, 0, true ><<<gy, blk, 0, stream>>>(y,    k_w1, k_b1, bufA, 128, 512);
  conv3x3_k<bf16,  bf16, 1, false><<<gy, blk, 0, stream>>>(bufA, k_w2, k_b2, bufB, 128, 512);
  // scores + softmax (consumes K before V overwrites bufB)
  attn_dot_k<<<dim3(4096), dim3(128), 0, stream>>>(qg, bufB, u, pb);
  // V path
  conv3x3_k<float, bf16, 0, true ><<<gy, blk, 0, stream>>>(y,    v_w1, v_b1, bufA, 128, 512);
  conv3x3_k<bf16,  bf16, 1, false><<<gy, blk, 0, stream>>>(bufA, v_w2, v_b2, bufB, 128, 512);
  // P @ V
  attn_pv_k<<<dim3(4096), dim3(128), 0, stream>>>(pb, bufB, u, ab);
  // proj
  conv3x3_k<float, float, 0, true ><<<gx, blk, 0, stream>>>(ab, proj_w, proj_b, out, 32, 32);
}

// Round 2
// 562.958 us; speedup vs baseline: 11.6398x; 11.6398x over previous
//
#include <hip/hip_runtime.h>
#include <stdint.h>

typedef __attribute__((ext_vector_type(4))) float f32x4;
typedef __attribute__((ext_vector_type(8))) short s16x8;

__device__ inline short bf16b(float f) {
  uint32_t x = __float_as_uint(f);
  return (short)((x + 0x7fffu + ((x >> 16) & 1u)) >> 16);  // RNE, finite inputs
}
__device__ inline float bfu(uint16_t u) { return __uint_as_float(((uint32_t)u) << 16); }

// ---------------- weight pack: (co,ci,3,3) f32 -> B-fragment order bf16 ----------------
// dst frag layout: [tap(9)][cichunk(4)][n16blk(8)][lane(64)][8]
// lane l, elem j: co = n16blk*16 + (l&15), ci = cichunk*32 + (l>>4)*8 + j
__global__ __launch_bounds__(256) void packw_k(
    const float* w0, const float* w1, const float* w2, const float* w3,
    const float* w4, const float* w5, const float* w6, s16x8* dst) {
  const float* srcs[7] = {w0, w1, w2, w3, w4, w5, w6};
  const int widx = blockIdx.y;
  const float* src = srcs[widx];
  const int gid = blockIdx.x * 256 + threadIdx.x;  // [0,18432)
  const int lane = gid & 63, frag = gid >> 6;      // frag < 288
  const int nblk = frag & 7, cc = (frag >> 3) & 3, tap = frag >> 5;
  const int co = nblk * 16 + (lane & 15);
  const int cib = cc * 32 + (lane >> 4) * 8;
  s16x8 v;
#pragma unroll
  for (int j = 0; j < 8; ++j)
    v[j] = bf16b(src[((size_t)co * 128 + cib + j) * 9 + tap]);
  dst[(size_t)widx * 18432 + (size_t)frag * 64 + lane] = v;
}

// ---------------- NCHW f32 -> NHWC bf16 ----------------
template <int TW>
__global__ __launch_bounds__(256) void nchw2nhwc_k(
    const float* __restrict__ in, uint16_t* __restrict__ out, int H, int W) {
  __shared__ float tile[128][TW + 1];
  const int b = blockIdx.z, h = blockIdx.y, w0 = blockIdx.x * TW;
  for (int idx = threadIdx.x; idx < 128 * TW; idx += 256) {
    int c = idx / TW, w = idx - c * TW;
    tile[c][w] = in[(((size_t)b * 128 + c) * H + h) * W + w0 + w];
  }
  __syncthreads();
  for (int idx = threadIdx.x; idx < TW * 16; idx += 256) {
    int w = idx >> 4, cg = idx & 15;
    s16x8 v;
#pragma unroll
    for (int j = 0; j < 8; ++j) v[j] = bf16b(tile[cg * 8 + j][w]);
    *reinterpret_cast<s16x8*>(out + ((((size_t)b * H + h) * W + w0 + w) << 7) + cg * 8) = v;
  }
}

// ---------------- MFMA conv: 3x3, Cin=Cout=128, SAME pad, NHWC bf16 input ----------------
// Block: ROWS x COLS pixel tile x 128 Cout. 256 thr = 4 waves (2x2), wave tile 64M x 64N.
// K = 9 taps x 128 ci, ci chunked by 32 (one MFMA K), LDS double-buffered input only.
// OMODE: 0 = NHWC, 1 = (b,w,h,e) gather, 3 = NCHW
template <int COLS, int ROWS, int OMODE, bool RELU, typename Tout, int SPT>
__global__ __launch_bounds__(256, 2) void convmf_k(
    const uint16_t* __restrict__ in, const s16x8* __restrict__ wpk,
    const float* __restrict__ bias, Tout* __restrict__ out, int H, int W) {
  constexpr int CP = COLS + 2, RP = ROWS + 2;
  constexpr int SLOTS = RP * CP * 4;  // 16B slots: [row][col][kblk]
  constexpr int LOGC = (COLS == 128) ? 7 : 5;
  __shared__ s16x8 lds[2][SLOTS];
  const int b = blockIdx.z, r0 = blockIdx.y * ROWS, c0 = blockIdx.x * COLS;
  const int tid = threadIdx.x, lane = tid & 63, wv = tid >> 6;
  const int wm = wv >> 1, wn = wv & 1;

  f32x4 acc[4][4];
#pragma unroll
  for (int i = 0; i < 4; ++i)
#pragma unroll
    for (int j = 0; j < 4; ++j) acc[i][j] = (f32x4){0.f, 0.f, 0.f, 0.f};

  s16x8 sreg[SPT];
  const size_t inb = (size_t)b * H * W;

  // stage chunk 0 (load->regs, write->LDS buf0)
#pragma unroll
  for (int i = 0; i < SPT; ++i) {
    int s = tid + i * 256;
    s16x8 v;
#pragma unroll
    for (int j = 0; j < 8; ++j) v[j] = 0;
    if (s < SLOTS) {
      int r = s / (CP * 4); int rem = s - r * (CP * 4); int c = rem >> 2; int k = rem & 3;
      int gr = r0 + r - 1, gc = c0 + c - 1;
      if (gr >= 0 && gr < H && gc >= 0 && gc < W)
        v = *reinterpret_cast<const s16x8*>(in + ((inb + (size_t)gr * W + gc) << 7) + k * 8);
    }
    sreg[i] = v;
  }
#pragma unroll
  for (int i = 0; i < SPT; ++i) { int s = tid + i * 256; if (s < SLOTS) lds[0][s] = sreg[i]; }

#pragma unroll 1
  for (int chunk = 0; chunk < 4; ++chunk) {
    if (chunk < 3) {  // T14: issue next chunk's global loads before compute
#pragma unroll
      for (int i = 0; i < SPT; ++i) {
        int s = tid + i * 256;
        s16x8 v;
#pragma unroll
        for (int j = 0; j < 8; ++j) v[j] = 0;
        if (s < SLOTS) {
          int r = s / (CP * 4); int rem = s - r * (CP * 4); int c = rem >> 2; int k = rem & 3;
          int gr = r0 + r - 1, gc = c0 + c - 1;
          if (gr >= 0 && gr < H && gc >= 0 && gc < W)
            v = *reinterpret_cast<const s16x8*>(
                in + ((inb + (size_t)gr * W + gc) << 7) + (chunk + 1) * 32 + k * 8);
        }
        sreg[i] = v;
      }
    }
    __syncthreads();  // lds[chunk&1] ready for all waves
    const s16x8* Lb = lds[chunk & 1];
#pragma unroll
    for (int tap = 0; tap < 9; ++tap) {
      const int ky = tap / 3, kx = tap % 3;
      s16x8 bfr[4];
      const s16x8* wp = wpk + (((size_t)(tap * 4 + chunk) * 8) + wn * 4) * 64 + lane;
#pragma unroll
      for (int nf = 0; nf < 4; ++nf) bfr[nf] = wp[nf * 64];  // B frags from L2
#pragma unroll
      for (int mf = 0; mf < 4; ++mf) {
        const int mb = wm * 64 + mf * 16;
        const int mrow = mb >> LOGC, mcol = mb & (COLS - 1);
        s16x8 af = Lb[(((mrow + ky) * CP) + mcol + (lane & 15) + kx) * 4 + (lane >> 4)];
#pragma unroll
        for (int nf = 0; nf < 4; ++nf)
          acc[mf][nf] = __builtin_amdgcn_mfma_f32_16x16x32_bf16(af, bfr[nf], acc[mf][nf], 0, 0, 0);
      }
    }
    if (chunk < 3) {  // write next chunk (other buffer; safe: last read pre-barrier)
      s16x8* Lw = lds[(chunk + 1) & 1];
#pragma unroll
      for (int i = 0; i < SPT; ++i) { int s = tid + i * 256; if (s < SLOTS) Lw[s] = sreg[i]; }
    }
  }

  // epilogue: C/D mapping col=lane&15 (=e), row=(lane>>4)*4+reg (=pixel)
#pragma unroll
  for (int nf = 0; nf < 4; ++nf) {
    const int e = wn * 64 + nf * 16 + (lane & 15);
    const float bv = bias[e];
#pragma unroll
    for (int mf = 0; mf < 4; ++mf) {
      const int mb = wm * 64 + mf * 16 + (lane >> 4) * 4;
#pragma unroll
      for (int r = 0; r < 4; ++r) {
        const int m = mb + r;
        const int gr = r0 + (m >> LOGC), gc = c0 + (m & (COLS - 1));
        float v = acc[mf][nf][r] + bv;
        if (RELU) v = fmaxf(v, 0.f);
        size_t idx;
        if (OMODE == 0)      idx = (((size_t)b * H + gr) * W + gc) * 128 + e;
        else if (OMODE == 1) idx = (((size_t)b * W + gc) * H + gr) * 128 + e;
        else                 idx = (((size_t)b * 128 + e) * H + gr) * W + gc;
        if constexpr (sizeof(Tout) == 2) ((uint16_t*)out)[idx] = (uint16_t)bf16b(v);
        else out[idx] = v;
      }
    }
  }
}

// ---------------- attention: dot + softmax ----------------
__global__ __launch_bounds__(128) void attn_dot_k(
    const float* __restrict__ qg, const uint16_t* __restrict__ Kg,
    const int* __restrict__ u, float* __restrict__ pout) {
  const int bs = blockIdx.x;
  const int b = bs >> 10;
  const int tid = threadIdx.x;  // h
  __shared__ float sq[128], sd[128];
  sq[tid] = qg[(size_t)bs * 128 + tid];
  int w = u[bs]; w = w < 0 ? 0 : (w > 511 ? 511 : w);
  __syncthreads();
  const uint32_t* kp = reinterpret_cast<const uint32_t*>(
      Kg + (((size_t)b * 512 + w) * 128 + tid) * 128);
  float acc = 0.f;
#pragma unroll 8
  for (int i = 0; i < 64; ++i) {
    uint32_t v = kp[i];
    acc = fmaf(sq[2 * i],     __uint_as_float(v << 16), acc);
    acc = fmaf(sq[2 * i + 1], __uint_as_float(v & 0xffff0000u), acc);
  }
  sd[tid] = acc * 0.17677669529663687f;
  __syncthreads();
  float mx = -1e30f;
  for (int i = 0; i < 128; ++i) mx = fmaxf(mx, sd[i]);
  float e = expf(sd[tid] - mx);
  __syncthreads();
  sd[tid] = e;
  __syncthreads();
  float sum = 0.f;
  for (int i = 0; i < 128; ++i) sum += sd[i];
  pout[(size_t)bs * 128 + tid] = e / sum;
}

// ---------------- attention: P @ V_gathered -> NHWC bf16 ----------------
__global__ __launch_bounds__(128) void attn_pv_k(
    const float* __restrict__ pin, const uint16_t* __restrict__ Vg,
    const int* __restrict__ u, uint16_t* __restrict__ aout) {
  const int bs = blockIdx.x;
  const int b = bs >> 10;
  const int tid = threadIdx.x;  // e
  __shared__ float sp[128];
  sp[tid] = pin[(size_t)bs * 128 + tid];
  int w = u[bs]; w = w < 0 ? 0 : (w > 511 ? 511 : w);
  __syncthreads();
  const uint16_t* vp = Vg + ((size_t)b * 512 + w) * 16384 + tid;
  float acc = 0.f;
#pragma unroll 8
  for (int h = 0; h < 128; ++h)
    acc = fmaf(sp[h], bfu(vp[h * 128]), acc);
  aout[(size_t)bs * 128 + tid] = (uint16_t)bf16b(acc);
}

// ---------------- launch ----------------
extern "C" void kernel_launch(void* const* d_in, const int* in_sizes, int n_in,
                              void* d_out, int out_size, void* d_ws, size_t ws_size,
                              hipStream_t stream) {
  const float* x      = (const float*)d_in[0];
  const float* y      = (const float*)d_in[1];
  const int*   u      = (const int*)d_in[2];
  const float* q_w1   = (const float*)d_in[3];
  const float* q_b1   = (const float*)d_in[4];
  const float* q_w2   = (const float*)d_in[5];
  const float* q_b2   = (const float*)d_in[6];
  const float* k_w1   = (const float*)d_in[7];
  const float* k_b1   = (const float*)d_in[8];
  const float* k_w2   = (const float*)d_in[9];
  const float* k_b2   = (const float*)d_in[10];
  const float* v_w1   = (const float*)d_in[11];
  const float* v_b1   = (const float*)d_in[12];
  const float* v_w2   = (const float*)d_in[13];
  const float* v_b2   = (const float*)d_in[14];
  const float* proj_w = (const float*)d_in[15];
  const float* proj_b = (const float*)d_in[16];
  float* out = (float*)d_out;

  char* ws = (char*)d_ws;
  const size_t BIG = (size_t)4 * 128 * 512 * 128 * 2;  // 67,108,864 (NHWC bf16)
  uint16_t* A   = (uint16_t*)ws;                        // ybf / K / V
  uint16_t* Bb  = (uint16_t*)(ws + BIG);                // k1 / v1
  float*    qg  = (float*)(ws + 2 * BIG);               // 2 MB (b,s,e) f32
  char*     scr = ws + 2 * BIG + (size_t)(2 << 20);     // 2 MB shared region
  uint16_t* xbf = (uint16_t*)scr;                       // 1 MB (dead after q path)
  uint16_t* t1  = (uint16_t*)(scr + (1 << 20));         // 1 MB (dead after q path)
  float*    pb  = (float*)scr;                          // 2 MB (after q path)
  uint16_t* ab  = (uint16_t*)(ws + 2 * BIG + (size_t)(4 << 20));  // 1 MB
  s16x8*    wpk = (s16x8*)(ws + 2 * BIG + (size_t)(5 << 20));     // 7 x 288KB

  // pack weights: [q1,q2,k1,k2,v1,v2,proj]
  packw_k<<<dim3(72, 7), 256, 0, stream>>>(q_w1, q_w2, k_w1, k_w2, v_w1, v_w2, proj_w, wpk);
  // input transforms
  nchw2nhwc_k<32><<<dim3(1, 32, 4), 256, 0, stream>>>(x, xbf, 32, 32);
  nchw2nhwc_k<64><<<dim3(8, 128, 4), 256, 0, stream>>>(y, A, 128, 512);
  // Q path
  convmf_k<32, 4, 0, true,  uint16_t, 4><<<dim3(1, 8, 4), 256, 0, stream>>>(xbf, wpk + 0 * 18432, q_b1, t1, 32, 32);
  convmf_k<32, 4, 0, false, float,    4><<<dim3(1, 8, 4), 256, 0, stream>>>(t1,  wpk + 1 * 18432, q_b2, qg, 32, 32);
  // K path
  convmf_k<128, 1, 0, true,  uint16_t, 7><<<dim3(4, 128, 4), 256, 0, stream>>>(A,  wpk + 2 * 18432, k_b1, Bb, 128, 512);
  convmf_k<128, 1, 1, false, uint16_t, 7><<<dim3(4, 128, 4), 256, 0, stream>>>(Bb, wpk + 3 * 18432, k_b2, A, 128, 512);
  attn_dot_k<<<dim3(4096), 128, 0, stream>>>(qg, A, u, pb);
  // V path (re-transform y: A held K until attn_dot)
  nchw2nhwc_k<64><<<dim3(8, 128, 4), 256, 0, stream>>>(y, A, 128, 512);
  convmf_k<128, 1, 0, true,  uint16_t, 7><<<dim3(4, 128, 4), 256, 0, stream>>>(A,  wpk + 4 * 18432, v_b1, Bb, 128, 512);
  convmf_k<128, 1, 1, false, uint16_t, 7><<<dim3(4, 128, 4), 256, 0, stream>>>(Bb, wpk + 5 * 18432, v_b2, A, 128, 512);
  attn_pv_k<<<dim3(4096), 128, 0, stream>>>(pb, A, u, ab);
  // proj
  convmf_k<32, 4, 3, true, float, 4><<<dim3(1, 8, 4), 256, 0, stream>>>(ab, wpk + 6 * 18432, proj_b, out, 32, 32);
}

// Round 3
// 488.303 us; speedup vs baseline: 13.4194x; 1.1529x over previous
//
#include <hip/hip_runtime.h>
#include <stdint.h>

typedef __attribute__((ext_vector_type(16))) float f32x16;
typedef __attribute__((ext_vector_type(8))) short s16x8;

__device__ inline short bf16b(float f) {
  uint32_t x = __float_as_uint(f);
  return (short)((x + 0x7fffu + ((x >> 16) & 1u)) >> 16);  // RNE, finite inputs
}
__device__ inline float bfu(uint16_t u) { return __uint_as_float(((uint32_t)u) << 16); }

__device__ inline void gll16(const void* g, void* l) {
  __builtin_amdgcn_global_load_lds((const __attribute__((address_space(1))) void*)g,
                                   (__attribute__((address_space(3))) void*)l, 16, 0, 0);
}

// ---------------- weight pack: (co,ci,3,3) f32 -> 32x32x16 B-fragment order ----------------
// frag idx = ((tap*4 + chunk)*2 + ks)*4 + nblk ; lane l elem j:
//   co = nblk*32 + (l&31), ci = chunk*32 + ks*16 + (l>>5)*8 + j
__global__ __launch_bounds__(256) void packw_k(
    const float* w0, const float* w1, const float* w2, const float* w3,
    const float* w4, const float* w5, const float* w6, s16x8* dst) {
  const float* srcs[7] = {w0, w1, w2, w3, w4, w5, w6};
  const int widx = blockIdx.y;
  const float* src = srcs[widx];
  const int gid = blockIdx.x * 256 + threadIdx.x;  // [0,18432)
  const int lane = gid & 63, frag = gid >> 6;      // frag < 288
  const int nblk = frag & 3, ks = (frag >> 2) & 1, chunk = (frag >> 3) & 3, tap = frag >> 5;
  const int co = nblk * 32 + (lane & 31);
  const int cib = chunk * 32 + ks * 16 + (lane >> 5) * 8;
  s16x8 v;
#pragma unroll
  for (int j = 0; j < 8; ++j)
    v[j] = bf16b(src[((size_t)co * 128 + cib + j) * 9 + tap]);
  dst[(size_t)widx * 18432 + (size_t)frag * 64 + lane] = v;
}

// ---------------- NCHW f32 -> NHWC bf16 ----------------
template <int TW>
__global__ __launch_bounds__(256) void nchw2nhwc_k(
    const float* __restrict__ in, uint16_t* __restrict__ out, int H, int W) {
  __shared__ float tile[128][TW + 1];
  const int b = blockIdx.z, h = blockIdx.y, w0 = blockIdx.x * TW;
  for (int idx = threadIdx.x; idx < 128 * TW; idx += 256) {
    int c = idx / TW, w = idx - c * TW;
    tile[c][w] = in[(((size_t)b * 128 + c) * H + h) * W + w0 + w];
  }
  __syncthreads();
  for (int idx = threadIdx.x; idx < TW * 16; idx += 256) {
    int w = idx >> 4, cg = idx & 15;
    s16x8 v;
#pragma unroll
    for (int j = 0; j < 8; ++j) v[j] = bf16b(tile[cg * 8 + j][w]);
    *reinterpret_cast<s16x8*>(out + ((((size_t)b * H + h) * W + w0 + w) << 7) + cg * 8) = v;
  }
}

// ---------------- MFMA conv: 3x3, Cin=Cout=128, SAME pad, NHWC bf16 input ----------------
// Tile: 8 rows x 32 cols x 128 co. 4 waves: wm(2) x wn(2); wave = 128 px x 64 co,
// 32x32x16 MFMA, acc 4x2 f32x16. Input staged via global_load_lds, k-major LDS
// [kq(4)][row(10)][col(34)] 16B slots, double-buffered; one barrier per 32-ci chunk,
// issued-early loads covered by MFMA phase. Weights streamed from L2, 1-step prefetch.
// OMODE: 0 = NHWC, 1 = (b,w,h,e) gather, 3 = NCHW
template <int OMODE, bool RELU, typename Tout>
__global__ __launch_bounds__(256, 2) void convmf2_k(
    const uint16_t* __restrict__ in, const s16x8* __restrict__ wpk,
    const float* __restrict__ bias, Tout* __restrict__ out,
    const uint16_t* __restrict__ zp, int H, int W) {
  constexpr int CP = 34, RPCP = 10 * 34;  // 340
  constexpr int SLOTS = 4 * RPCP;         // 1360
  constexpr int SPT = 6;                  // 6*256 = 1536 padded slots
  __shared__ s16x8 lds[2][SPT * 256];
  const int b = blockIdx.z, r0 = blockIdx.y * 8, c0 = blockIdx.x * 32;
  const int tid = threadIdx.x, lane = tid & 63;
  const int wv = tid >> 6, wm = wv >> 1, wn = wv & 1;
  const int wbase = tid & 192;

  // per-slot global source addresses (once)
  const uint16_t* gsrc[SPT];
#pragma unroll
  for (int i = 0; i < SPT; ++i) {
    const int s = tid + i * 256;
    const int kq = s / RPCP;
    const int rem = s - kq * RPCP;
    const int r = rem / CP, c = rem - r * CP;
    const int gr = r0 + r - 1, gc = c0 + c - 1;
    const bool ok = (s < SLOTS) && gr >= 0 && gr < H && gc >= 0 && gc < W;
    gsrc[i] = ok ? (in + (((size_t)b * H + gr) * W + gc) * 128 + kq * 8) : zp;
  }

  // prologue: stage chunk 0 into buf 0
#pragma unroll
  for (int i = 0; i < SPT; ++i) gll16(gsrc[i], &lds[0][wbase + i * 256]);

  f32x16 acc[4][2];
#pragma unroll
  for (int i = 0; i < 4; ++i)
#pragma unroll
    for (int j = 0; j < 2; ++j)
#pragma unroll
      for (int r = 0; r < 16; ++r) acc[i][j][r] = 0.f;

  const int rowb = wm * 4 * CP + (lane >> 5) * RPCP + (lane & 31);
  __syncthreads();

#pragma unroll 1
  for (int chunk = 0; chunk < 4; ++chunk) {
    const int cb = chunk & 1;
    if (chunk < 3) {  // issue next chunk's DMA; completes under this chunk's MFMA
#pragma unroll
      for (int i = 0; i < SPT; ++i)
        gll16(gsrc[i] + (chunk + 1) * 32, &lds[cb ^ 1][wbase + i * 256]);
    }
    const s16x8* __restrict__ Lb = &lds[cb][rowb];
    const s16x8* __restrict__ wpc = wpk + ((size_t)chunk * 8 + wn * 2) * 64 + lane;
    s16x8 bwA[2], bwB[2];
    bwA[0] = wpc[0]; bwA[1] = wpc[64];
#pragma unroll
    for (int t9 = 0; t9 < 18; ++t9) {  // t9 = tap*2 + ks
      const int tap = t9 >> 1, ks = t9 & 1;
      const int ky = tap / 3, kx = tap - ky * 3;
      if (t9 < 17) {  // prefetch next (tap,ks) weight pair
        const int tn = t9 + 1, tapn = tn >> 1, ksn = tn & 1;
        s16x8* nx = (t9 & 1) ? bwA : bwB;
        nx[0] = wpc[tapn * 2048 + ksn * 256];
        nx[1] = wpc[tapn * 2048 + ksn * 256 + 64];
      }
      const s16x8* cw = (t9 & 1) ? bwB : bwA;
#pragma unroll
      for (int mf = 0; mf < 4; ++mf) {
        const s16x8 av = Lb[ks * (2 * RPCP) + (mf + ky) * CP + kx];
        acc[mf][0] = __builtin_amdgcn_mfma_f32_32x32x16_bf16(av, cw[0], acc[mf][0], 0, 0, 0);
        acc[mf][1] = __builtin_amdgcn_mfma_f32_32x32x16_bf16(av, cw[1], acc[mf][1], 0, 0, 0);
      }
    }
    if (chunk < 3) __syncthreads();
  }

  // epilogue: C/D map col(co)=lane&31, image-col = (reg&3)+8*(reg>>2)+4*(lane>>5)
#pragma unroll
  for (int nf = 0; nf < 2; ++nf) {
    const int co = wn * 64 + nf * 32 + (lane & 31);
    const float bv = bias[co];
#pragma unroll
    for (int mf = 0; mf < 4; ++mf) {
      const int gr = r0 + wm * 4 + mf;
#pragma unroll
      for (int reg = 0; reg < 16; ++reg) {
        const int gc = c0 + (reg & 3) + 8 * (reg >> 2) + 4 * (lane >> 5);
        float v = acc[mf][nf][reg] + bv;
        if (RELU) v = fmaxf(v, 0.f);
        size_t idx;
        if (OMODE == 0)      idx = (((size_t)b * H + gr) * W + gc) * 128 + co;
        else if (OMODE == 1) idx = (((size_t)b * W + gc) * H + gr) * 128 + co;
        else                 idx = (((size_t)b * 128 + co) * H + gr) * W + gc;
        if constexpr (sizeof(Tout) == 2) ((uint16_t*)out)[idx] = (uint16_t)bf16b(v);
        else out[idx] = v;
      }
    }
  }
}

// ---------------- attention: dot + softmax ----------------
__global__ __launch_bounds__(128) void attn_dot_k(
    const float* __restrict__ qg, const uint16_t* __restrict__ Kg,
    const int* __restrict__ u, float* __restrict__ pout) {
  const int bs = blockIdx.x;
  const int b = bs >> 10;
  const int tid = threadIdx.x;  // h
  __shared__ float sq[128], sd[128];
  sq[tid] = qg[(size_t)bs * 128 + tid];
  int w = u[bs]; w = w < 0 ? 0 : (w > 511 ? 511 : w);
  __syncthreads();
  const uint32_t* kp = reinterpret_cast<const uint32_t*>(
      Kg + (((size_t)b * 512 + w) * 128 + tid) * 128);
  float acc = 0.f;
#pragma unroll 8
  for (int i = 0; i < 64; ++i) {
    uint32_t v = kp[i];
    acc = fmaf(sq[2 * i],     __uint_as_float(v << 16), acc);
    acc = fmaf(sq[2 * i + 1], __uint_as_float(v & 0xffff0000u), acc);
  }
  sd[tid] = acc * 0.17677669529663687f;
  __syncthreads();
  float mx = -1e30f;
  for (int i = 0; i < 128; ++i) mx = fmaxf(mx, sd[i]);
  float e = expf(sd[tid] - mx);
  __syncthreads();
  sd[tid] = e;
  __syncthreads();
  float sum = 0.f;
  for (int i = 0; i < 128; ++i) sum += sd[i];
  pout[(size_t)bs * 128 + tid] = e / sum;
}

// ---------------- attention: P @ V_gathered -> (b,s,e) bf16 ----------------
__global__ __launch_bounds__(128) void attn_pv_k(
    const float* __restrict__ pin, const uint16_t* __restrict__ Vg,
    const int* __restrict__ u, uint16_t* __restrict__ aout) {
  const int bs = blockIdx.x;
  const int b = bs >> 10;
  const int tid = threadIdx.x;  // e
  __shared__ float sp[128];
  sp[tid] = pin[(size_t)bs * 128 + tid];
  int w = u[bs]; w = w < 0 ? 0 : (w > 511 ? 511 : w);
  __syncthreads();
  const uint16_t* vp = Vg + ((size_t)b * 512 + w) * 16384 + tid;
  float acc = 0.f;
#pragma unroll 8
  for (int h = 0; h < 128; ++h)
    acc = fmaf(sp[h], bfu(vp[h * 128]), acc);
  aout[(size_t)bs * 128 + tid] = (uint16_t)bf16b(acc);
}

// ---------------- launch ----------------
extern "C" void kernel_launch(void* const* d_in, const int* in_sizes, int n_in,
                              void* d_out, int out_size, void* d_ws, size_t ws_size,
                              hipStream_t stream) {
  const float* x      = (const float*)d_in[0];
  const float* y      = (const float*)d_in[1];
  const int*   u      = (const int*)d_in[2];
  const float* q_w1   = (const float*)d_in[3];
  const float* q_b1   = (const float*)d_in[4];
  const float* q_w2   = (const float*)d_in[5];
  const float* q_b2   = (const float*)d_in[6];
  const float* k_w1   = (const float*)d_in[7];
  const float* k_b1   = (const float*)d_in[8];
  const float* k_w2   = (const float*)d_in[9];
  const float* k_b2   = (const float*)d_in[10];
  const float* v_w1   = (const float*)d_in[11];
  const float* v_b1   = (const float*)d_in[12];
  const float* v_w2   = (const float*)d_in[13];
  const float* v_b2   = (const float*)d_in[14];
  const float* proj_w = (const float*)d_in[15];
  const float* proj_b = (const float*)d_in[16];
  float* out = (float*)d_out;

  char* ws = (char*)d_ws;
  const size_t MB = 1 << 20;
  const size_t BIG = 64 * MB;
  const bool tierB = ws_size >= 203 * MB;  // 3 big buffers -> skip 2nd y-transform
  uint16_t* A  = (uint16_t*)ws;            // ybf (NHWC bf16)
  uint16_t* Bb = (uint16_t*)(ws + BIG);    // k1 / v1
  uint16_t* KV = tierB ? (uint16_t*)(ws + 2 * BIG) : A;  // K / V in (b,w,h,e)
  char* sm = ws + (tierB ? 3 : 2) * BIG;
  float*    qg  = (float*)sm;                    // 2 MB
  float*    pb  = (float*)(sm + 2 * MB);         // 2 MB
  uint16_t* xbf = (uint16_t*)(sm + 4 * MB);      // 1 MB
  uint16_t* t1  = (uint16_t*)(sm + 5 * MB);      // 1 MB
  uint16_t* ab  = (uint16_t*)(sm + 6 * MB);      // 1 MB
  s16x8*    wpk = (s16x8*)(sm + 7 * MB);         // ~2.02 MB
  uint16_t* zp  = (uint16_t*)(sm + 10 * MB);     // 1 KB zeros

  hipMemsetAsync(zp, 0, 1024, stream);
  packw_k<<<dim3(72, 7), 256, 0, stream>>>(q_w1, q_w2, k_w1, k_w2, v_w1, v_w2, proj_w, wpk);
  nchw2nhwc_k<32><<<dim3(1, 32, 4), 256, 0, stream>>>(x, xbf, 32, 32);
  nchw2nhwc_k<64><<<dim3(8, 128, 4), 256, 0, stream>>>(y, A, 128, 512);
  // Q path
  convmf2_k<0, true,  uint16_t><<<dim3(1, 4, 4), 256, 0, stream>>>(xbf, wpk + 0 * 18432, q_b1, t1, zp, 32, 32);
  convmf2_k<0, false, float   ><<<dim3(1, 4, 4), 256, 0, stream>>>(t1,  wpk + 1 * 18432, q_b2, qg, zp, 32, 32);
  // K path
  convmf2_k<0, true,  uint16_t><<<dim3(16, 16, 4), 256, 0, stream>>>(A,  wpk + 2 * 18432, k_b1, Bb, zp, 128, 512);
  convmf2_k<1, false, uint16_t><<<dim3(16, 16, 4), 256, 0, stream>>>(Bb, wpk + 3 * 18432, k_b2, KV, zp, 128, 512);
  attn_dot_k<<<dim3(4096), 128, 0, stream>>>(qg, KV, u, pb);
  // V path
  if (!tierB) nchw2nhwc_k<64><<<dim3(8, 128, 4), 256, 0, stream>>>(y, A, 128, 512);
  convmf2_k<0, true,  uint16_t><<<dim3(16, 16, 4), 256, 0, stream>>>(A,  wpk + 4 * 18432, v_b1, Bb, zp, 128, 512);
  convmf2_k<1, false, uint16_t><<<dim3(16, 16, 4), 256, 0, stream>>>(Bb, wpk + 5 * 18432, v_b2, KV, zp, 128, 512);
  attn_pv_k<<<dim3(4096), 128, 0, stream>>>(pb, KV, u, ab);
  // proj
  convmf2_k<3, true, float><<<dim3(1, 4, 4), 256, 0, stream>>>(ab, wpk + 6 * 18432, proj_b, out, zp, 32, 32);
}